// Round 18
// baseline (423.392 us; speedup 1.0000x reference)
//
#include <hip/hip_runtime.h>

typedef unsigned short u16;
typedef __bf16 bf16x8 __attribute__((ext_vector_type(8)));
typedef float f32x4 __attribute__((ext_vector_type(4)));

__device__ __forceinline__ u16 f2bf(float f) {
  unsigned u = __builtin_bit_cast(unsigned, f);
  u += 0x7FFFu + ((u >> 16) & 1u);
  return (u16)(u >> 16);
}

#define GLOAD16(g, l) __builtin_amdgcn_global_load_lds( \
    (const __attribute__((address_space(1))) unsigned int*)(const void*)(g), \
    (__attribute__((address_space(3))) unsigned int*)(void*)(l), 16, 0, 0)

// swizzled u16 index of 16B-chunk c (0..7) in row r of a 64-u16-wide LDS tile
#define SW(r, c) (((r) << 6) + ((((c) ^ ((r) & 7))) << 3))

#define QSCALE 0.03125f  // 1/sqrt(1024); __expf only (v_exp asm = TRANS hazard, R16 NaN)

// ---------------------------------------------------------------- merged transpose + f32->bf16
__global__ __launch_bounds__(256) void tconv_all(
    const float* __restrict__ Wq, const float* __restrict__ Wk,
    const float* __restrict__ Wv, const float* __restrict__ Wo,
    const float* __restrict__ W1, const float* __restrict__ W2,
    u16* __restrict__ wqkv, u16* __restrict__ wo,
    u16* __restrict__ w1t, u16* __restrict__ w2t) {
  __shared__ float t[32][33];
  const int b = blockIdx.x;
  const float* W;
  u16* Wt;
  int K, N, n0, k0;
  if (b < 4096) {
    int which = b >> 10, tt = b & 1023;
    K = 1024; N = 1024;
    n0 = (tt & 31) * 32; k0 = (tt >> 5) * 32;
    W = (which == 0) ? Wq : (which == 1) ? Wk : (which == 2) ? Wv : Wo;
    Wt = (which < 3) ? (wqkv + (size_t)which * 1024 * 1024) : wo;
  } else if (b < 7168) {
    int tt = b - 4096;
    K = 1024; N = 3072;
    n0 = (tt % 96) * 32; k0 = (tt / 96) * 32;
    W = W1; Wt = w1t;
  } else {
    int tt = b - 7168;
    K = 3072; N = 1024;
    n0 = (tt & 31) * 32; k0 = (tt >> 5) * 32;
    W = W2; Wt = w2t;
  }
  int tx = threadIdx.x, ty = threadIdx.y;
#pragma unroll
  for (int j = 0; j < 4; ++j)
    t[ty + j * 8][tx] = W[(size_t)(k0 + ty + j * 8) * N + n0 + tx];
  __syncthreads();
#pragma unroll
  for (int j = 0; j < 4; ++j)
    Wt[(size_t)(n0 + ty + j * 8) * K + k0 + tx] = f2bf(t[tx][ty + j * 8]);
}

// ---------------------------------------------------------------- posenc + layernorm
template <bool PE>
__global__ __launch_bounds__(256) void ln_row(const float* __restrict__ in,
                                              const float* __restrict__ g,
                                              const float* __restrict__ be,
                                              float* __restrict__ xout,
                                              u16* __restrict__ hout) {
  const int row = blockIdx.x;
  const int tid = threadIdx.x;
  const int s = row & 2047;
  float4 xv = *(const float4*)&in[(size_t)row * 1024 + tid * 4];
  float vals[4];
  const float* xp = (const float*)&xv;
#pragma unroll
  for (int j = 0; j < 4; ++j) {
    float v = xp[j];
    if (PE) {
      int d = tid * 4 + j;
      float freq = powf(10000.f, -2.f * (float)d * (1.f / 1024.f));
      float ang = (float)s * freq;
      v += (d & 1) ? cosf(ang) : sinf(ang);
    }
    vals[j] = v;
  }
  if (PE) {
    float4 st;
    float* sp = (float*)&st;
#pragma unroll
    for (int j = 0; j < 4; ++j) sp[j] = vals[j];
    *(float4*)&xout[(size_t)row * 1024 + tid * 4] = st;
  }
  float sum = vals[0] + vals[1] + vals[2] + vals[3];
  float sq = vals[0] * vals[0] + vals[1] * vals[1] + vals[2] * vals[2] + vals[3] * vals[3];
#pragma unroll
  for (int d = 1; d < 64; d <<= 1) {
    sum += __shfl_xor(sum, d);
    sq += __shfl_xor(sq, d);
  }
  __shared__ float red[8];
  int wave = tid >> 6, lane = tid & 63;
  if (lane == 0) { red[wave] = sum; red[4 + wave] = sq; }
  __syncthreads();
  sum = red[0] + red[1] + red[2] + red[3];
  sq = red[4] + red[5] + red[6] + red[7];
  float mu = sum * (1.f / 1024.f);
  float var = sq * (1.f / 1024.f) - mu * mu;
  float rv = rsqrtf(var + 1e-5f);
#pragma unroll
  for (int j = 0; j < 4; ++j) {
    int d = tid * 4 + j;
    hout[(size_t)row * 1024 + d] = f2bf((vals[j] - mu) * rv * g[d] + be[d]);
  }
}

// ---------------------------------------------------------------- GEMM  C = A @ Bt^T
// 128x128 tile, BK=64, 4 waves, 4 blocks/CU, swizzled, 0 conflicts.
// Grids (24,64)/(8,64) -- measured best (R13/R15).
#define EPI_QKV 0
#define EPI_OPROJ 1
#define EPI_FFN1 2
#define EPI_FFN2 3

template <int EPI>
__global__ __launch_bounds__(256, 4) void gemm_bt(
    const u16* __restrict__ A, const u16* __restrict__ Bt, int M, int N, int K,
    const float* __restrict__ bias, const float* __restrict__ resid,
    float* __restrict__ outf, u16* __restrict__ outb,
    u16* __restrict__ oq, u16* __restrict__ okk, u16* __restrict__ ovt) {
  __shared__ __align__(16) u16 As[128 * 64];
  __shared__ __align__(16) u16 Bs[128 * 64];
  const int tid = threadIdx.x;
  const int wave = tid >> 6, lane = tid & 63;
  const int m0 = blockIdx.y * 128, n0 = blockIdx.x * 128;
  const int lrow = lane & 15, lhi = lane >> 4;
  const int wr = (wave >> 1) * 64, wc = (wave & 1) * 64;
  const int srow = tid >> 3;
  const int swsrc = ((tid & 7) ^ (srow & 7)) * 8;
  const u16* Ag = A + (size_t)(m0 + srow) * K + swsrc;
  const u16* Bg = Bt + (size_t)(n0 + srow) * K + swsrc;

  f32x4 acc[4][4] = {};

  for (int kt = 0; kt < K; kt += 64) {
#pragma unroll
    for (int j = 0; j < 4; ++j) {
      GLOAD16(Ag + (size_t)(j * 32) * K + kt, &As[j * 2048 + wave * 512]);
      GLOAD16(Bg + (size_t)(j * 32) * K + kt, &Bs[j * 2048 + wave * 512]);
    }
    __syncthreads();
    bf16x8 af[2][4], bfr[2][4];
#pragma unroll
    for (int kk = 0; kk < 2; ++kk) {
#pragma unroll
      for (int m = 0; m < 4; ++m)
        af[kk][m] = *(const bf16x8*)&As[SW(wr + m * 16 + lrow, kk * 4 + lhi)];
#pragma unroll
      for (int n = 0; n < 4; ++n)
        bfr[kk][n] = *(const bf16x8*)&Bs[SW(wc + n * 16 + lrow, kk * 4 + lhi)];
    }
#pragma unroll
    for (int kk = 0; kk < 2; ++kk)
#pragma unroll
      for (int m = 0; m < 4; ++m)
#pragma unroll
        for (int n = 0; n < 4; ++n)
          acc[m][n] = __builtin_amdgcn_mfma_f32_16x16x32_bf16(af[kk][m], bfr[kk][n], acc[m][n], 0, 0, 0);
    __syncthreads();
  }

#pragma unroll
  for (int m = 0; m < 4; ++m) {
#pragma unroll
    for (int n = 0; n < 4; ++n) {
#pragma unroll
      for (int i = 0; i < 4; ++i) {
        int row = m0 + wr + m * 16 + lhi * 4 + i;
        int col = n0 + wc + n * 16 + lrow;
        float v = acc[m][n][i];
        if (EPI == EPI_QKV) {
          int which = col >> 10, c = col & 1023;
          int h = c >> 6, hd = c & 63;
          int b = row >> 11, s = row & 2047;
          size_t qk = (((size_t)(b * 16 + h) * 2048 + s) << 6) + hd;
          if (which == 0) oq[qk] = f2bf(v * QSCALE);
          else if (which == 1) okk[qk] = f2bf(v);
          else ovt[((size_t)(b * 16 + h) * 64 + hd) * 2048 + s] = f2bf(v);
        } else if (EPI == EPI_OPROJ) {
          size_t idx = (size_t)row * 1024 + col;
          outf[idx] = v + resid[idx];
        } else if (EPI == EPI_FFN1) {
          float t = v + bias[col];
          t = t > 0.f ? t : 0.01f * t;
          outb[(size_t)row * 3072 + col] = f2bf(t);
        } else {  // FFN2
          size_t idx = (size_t)row * 1024 + col;
          outf[idx] = v + bias[col] + resid[idx];
        }
      }
    }
  }
}

// ---------------------------------------------------------------- flash attention
// 4-wave / 128-q-row blocks, 1024 blocks, LDS 40KB (K double-buffered, V
// SINGLE-buffered, Pl 16K) -> 4 blocks/CU, ALL blocks co-resident, zero tail.
// Rationale: R17 showed extra waves in the SAME block don't help (shared
// barrier); what hides the drain stalls is more INDEPENDENT blocks per CU
// (m114; gemm_bt at 4 blocks/CU is the in-session proof).  Cost: one extra
// barrier per tile (post-PV, frees Vl) + V latency at next tile-start
// barrier -- covered by the other 3 blocks' compute.  __expf softmax, no-max,
// swizzled, 0 conflicts, XCD remap.
__global__ __launch_bounds__(256, 4) void attn_fwd(const u16* __restrict__ qb,
                                                   const u16* __restrict__ kbuf,
                                                   const u16* __restrict__ vtb,
                                                   u16* __restrict__ ob) {
  __shared__ __align__(16) u16 Kl[2][64 * 64];
  __shared__ __align__(16) u16 Vl[64 * 64];
  __shared__ __align__(16) u16 Pl[128 * 64];
  const int tid = threadIdx.x, wave = tid >> 6, lane = tid & 63;
  const int wid = (blockIdx.x & 7) * 128 + (blockIdx.x >> 3);
  const int bh = wid >> 4, qt = wid & 15;
  const int lrow = lane & 15, lhi = lane >> 4;
  const u16* Qg = qb + (((size_t)bh * 2048 + qt * 128) << 6);
  const u16* Kg = kbuf + ((size_t)bh * 2048 << 6);
  const u16* Vg = vtb + (size_t)bh * 64 * 2048;
  const int srow = tid >> 3;
  const int swsrc = ((tid & 7) ^ (srow & 7)) * 8;

  // stage Q -> Pl, K tile0 -> Kl[0], V tile0 -> Vl
#pragma unroll
  for (int j = 0; j < 4; ++j)
    GLOAD16(Qg + (size_t)(srow + j * 32) * 64 + swsrc, &Pl[j * 2048 + wave * 512]);
#pragma unroll
  for (int j = 0; j < 2; ++j) {
    int r = srow + j * 32;
    GLOAD16(Kg + (size_t)r * 64 + swsrc, &Kl[0][j * 2048 + wave * 512]);
    GLOAD16(Vg + (size_t)r * 2048 + swsrc, &Vl[j * 2048 + wave * 512]);
  }
  __syncthreads();

  bf16x8 qf[2][2];
#pragma unroll
  for (int m = 0; m < 2; ++m)
#pragma unroll
    for (int kk = 0; kk < 2; ++kk)
      qf[m][kk] = *(const bf16x8*)&Pl[SW(wave * 32 + m * 16 + lrow, kk * 4 + lhi)];
  // Pl rows [32*wave, 32*wave+32) are wave-private from here on

  f32x4 oacc[2][4] = {};
  float lsum[8];
#pragma unroll
  for (int i = 0; i < 8; ++i) lsum[i] = 0.f;

  int cur = 0;
  for (int kv = 0; kv < 2048; kv += 64) {
    if (kv) __syncthreads();  // K[cur] (staged last tile) + V (staged last tile) landed
    if (kv + 64 < 2048) {     // K prefetch flies under this whole tile
#pragma unroll
      for (int j = 0; j < 2; ++j)
        GLOAD16(Kg + (size_t)(kv + 64 + srow + j * 32) * 64 + swsrc,
                &Kl[cur ^ 1][j * 2048 + wave * 512]);
    }

    f32x4 sf[2][4] = {};
#pragma unroll
    for (int n = 0; n < 4; ++n) {
#pragma unroll
      for (int kk = 0; kk < 2; ++kk) {
        bf16x8 kf = *(const bf16x8*)&Kl[cur][SW(n * 16 + lrow, kk * 4 + lhi)];
        sf[0][n] = __builtin_amdgcn_mfma_f32_16x16x32_bf16(qf[0][kk], kf, sf[0][n], 0, 0, 0);
        sf[1][n] = __builtin_amdgcn_mfma_f32_16x16x32_bf16(qf[1][kk], kf, sf[1][n], 0, 0, 0);
      }
    }
    // no-max softmax: p = exp(s); per-lane partial row-sums only
#pragma unroll
    for (int m = 0; m < 2; ++m) {
#pragma unroll
      for (int i = 0; i < 4; ++i) {
        float rs = 0.f;
#pragma unroll
        for (int n = 0; n < 4; ++n) {
          float p = __expf(sf[m][n][i]);
          sf[m][n][i] = p;
          rs += p;
        }
        lsum[m * 4 + i] += rs;
      }
    }
    // P -> LDS (bf16, swizzled, wave-private rows; same-wave lgkmcnt orders it)
#pragma unroll
    for (int m = 0; m < 2; ++m)
#pragma unroll
      for (int n = 0; n < 4; ++n)
#pragma unroll
        for (int i = 0; i < 4; ++i) {
          int pr = wave * 32 + m * 16 + lhi * 4 + i;
          Pl[SW(pr, n * 2 + (lrow >> 3)) + (lrow & 7)] = f2bf(sf[m][n][i]);
        }
    // PV from the (single) V buffer
#pragma unroll
    for (int kk = 0; kk < 2; ++kk) {
      bf16x8 pf0 = *(const bf16x8*)&Pl[SW(wave * 32 + 0 + lrow, kk * 4 + lhi)];
      bf16x8 pf1 = *(const bf16x8*)&Pl[SW(wave * 32 + 16 + lrow, kk * 4 + lhi)];
#pragma unroll
      for (int n = 0; n < 4; ++n) {
        bf16x8 vf = *(const bf16x8*)&Vl[SW(n * 16 + lrow, kk * 4 + lhi)];
        oacc[0][n] = __builtin_amdgcn_mfma_f32_16x16x32_bf16(pf0, vf, oacc[0][n], 0, 0, 0);
        oacc[1][n] = __builtin_amdgcn_mfma_f32_16x16x32_bf16(pf1, vf, oacc[1][n], 0, 0, 0);
      }
    }
    __syncthreads();          // all waves done reading Vl -> safe to re-stage
    if (kv + 64 < 2048) {     // V stage; lands at next tile-start barrier
#pragma unroll
      for (int j = 0; j < 2; ++j)
        GLOAD16(Vg + (size_t)(srow + j * 32) * 2048 + kv + 64 + swsrc,
                &Vl[j * 2048 + wave * 512]);
    }
    cur ^= 1;
  }

#pragma unroll
  for (int idx = 0; idx < 8; ++idx)
#pragma unroll
    for (int d = 1; d < 16; d <<= 1)
      lsum[idx] += __shfl_xor(lsum[idx], d, 16);

  const int b = bh >> 4, h = bh & 15;
#pragma unroll
  for (int m = 0; m < 2; ++m)
#pragma unroll
    for (int i = 0; i < 4; ++i) {
      int qrow = qt * 128 + wave * 32 + m * 16 + lhi * 4 + i;
      float inv = 1.f / lsum[m * 4 + i];
#pragma unroll
      for (int n = 0; n < 4; ++n) {
        int hd = n * 16 + lrow;
        ob[((size_t)(b * 2048 + qrow)) * 1024 + h * 64 + hd] = f2bf(oacc[m][n][i] * inv);
      }
    }
}

// ---------------------------------------------------------------- launch
extern "C" void kernel_launch(void* const* d_in, const int* in_sizes, int n_in,
                              void* d_out, int out_size, void* d_ws, size_t ws_size,
                              hipStream_t stream) {
  const float* x = (const float*)d_in[0];
  const float* Wq = (const float*)d_in[1];
  const float* Wk = (const float*)d_in[2];
  const float* Wv = (const float*)d_in[3];
  const float* Wo = (const float*)d_in[4];
  const float* W1 = (const float*)d_in[5];
  const float* b1 = (const float*)d_in[6];
  const float* W2 = (const float*)d_in[7];
  const float* b2 = (const float*)d_in[8];
  const float* g1 = (const float*)d_in[9];
  const float* be1 = (const float*)d_in[10];
  const float* g2 = (const float*)d_in[11];
  const float* be2 = (const float*)d_in[12];

  char* ws = (char*)d_ws;
  const size_t MB = 1024 * 1024;
  float* x1 = (float*)(ws + 0);          // 32MB, becomes x2 in-place after OPROJ
  u16* h = (u16*)(ws + 32 * MB);         // 16MB (reused as h2)
  u16* q = (u16*)(ws + 48 * MB);         // 16MB
  u16* k = (u16*)(ws + 64 * MB);         // 16MB
  u16* vt = (u16*)(ws + 80 * MB);        // 16MB
  u16* o = (u16*)(ws + 96 * MB);         // 16MB
  u16* f = (u16*)(ws + 48 * MB);         // 48MB, aliases q/k/vt (dead after attn)
  u16* wqkv = (u16*)(ws + 112 * MB);     // 6MB
  u16* wo = (u16*)(ws + 118 * MB);       // 2MB
  u16* w1t = (u16*)(ws + 120 * MB);      // 6MB
  u16* w2t = (u16*)(ws + 126 * MB);      // 6MB -> 132MB total
  float* out = (float*)d_out;

  tconv_all<<<10240, dim3(32, 8), 0, stream>>>(Wq, Wk, Wv, Wo, W1, W2,
                                               wqkv, wo, w1t, w2t);

  ln_row<true><<<8192, 256, 0, stream>>>(x, g1, be1, x1, h);

  gemm_bt<EPI_QKV><<<dim3(24, 64), 256, 0, stream>>>(h, wqkv, 8192, 3072, 1024,
                                                     nullptr, nullptr, nullptr, nullptr,
                                                     q, k, vt);
  attn_fwd<<<1024, 256, 0, stream>>>(q, k, vt, o);

  gemm_bt<EPI_OPROJ><<<dim3(8, 64), 256, 0, stream>>>(o, wo, 8192, 1024, 1024,
                                                      nullptr, x1, x1, nullptr,
                                                      nullptr, nullptr, nullptr);
  ln_row<false><<<8192, 256, 0, stream>>>(x1, g2, be2, nullptr, h);

  gemm_bt<EPI_FFN1><<<dim3(24, 64), 256, 0, stream>>>(h, w1t, 8192, 3072, 1024,
                                                      b1, nullptr, nullptr, f,
                                                      nullptr, nullptr, nullptr);
  gemm_bt<EPI_FFN2><<<dim3(8, 64), 256, 0, stream>>>(f, w2t, 8192, 1024, 3072,
                                                     b2, x1, out, nullptr,
                                                     nullptr, nullptr, nullptr);
}

// Round 19
// 420.136 us; speedup vs baseline: 1.0077x; 1.0077x over previous
//
#include <hip/hip_runtime.h>

typedef unsigned short u16;
typedef __bf16 bf16x8 __attribute__((ext_vector_type(8)));
typedef float f32x4 __attribute__((ext_vector_type(4)));

__device__ __forceinline__ u16 f2bf(float f) {
  unsigned u = __builtin_bit_cast(unsigned, f);
  u += 0x7FFFu + ((u >> 16) & 1u);
  return (u16)(u >> 16);
}

#define GLOAD16(g, l) __builtin_amdgcn_global_load_lds( \
    (const __attribute__((address_space(1))) unsigned int*)(const void*)(g), \
    (__attribute__((address_space(3))) unsigned int*)(void*)(l), 16, 0, 0)

// swizzled u16 index of 16B-chunk c (0..7) in row r of a 64-u16-wide LDS tile
#define SW(r, c) (((r) << 6) + ((((c) ^ ((r) & 7))) << 3))
// 128-u16-wide variant: 16 chunks per row, XOR with r&15
#define SW128(r, c) (((r) << 7) + ((((c) ^ ((r) & 15))) << 3))

#define QSCALE 0.03125f  // 1/sqrt(1024); __expf only (v_exp asm = TRANS hazard, R16 NaN)

// ---------------------------------------------------------------- merged transpose + f32->bf16
__global__ __launch_bounds__(256) void tconv_all(
    const float* __restrict__ Wq, const float* __restrict__ Wk,
    const float* __restrict__ Wv, const float* __restrict__ Wo,
    const float* __restrict__ W1, const float* __restrict__ W2,
    u16* __restrict__ wqkv, u16* __restrict__ wo,
    u16* __restrict__ w1t, u16* __restrict__ w2t) {
  __shared__ float t[32][33];
  const int b = blockIdx.x;
  const float* W;
  u16* Wt;
  int K, N, n0, k0;
  if (b < 4096) {
    int which = b >> 10, tt = b & 1023;
    K = 1024; N = 1024;
    n0 = (tt & 31) * 32; k0 = (tt >> 5) * 32;
    W = (which == 0) ? Wq : (which == 1) ? Wk : (which == 2) ? Wv : Wo;
    Wt = (which < 3) ? (wqkv + (size_t)which * 1024 * 1024) : wo;
  } else if (b < 7168) {
    int tt = b - 4096;
    K = 1024; N = 3072;
    n0 = (tt % 96) * 32; k0 = (tt / 96) * 32;
    W = W1; Wt = w1t;
  } else {
    int tt = b - 7168;
    K = 3072; N = 1024;
    n0 = (tt & 31) * 32; k0 = (tt >> 5) * 32;
    W = W2; Wt = w2t;
  }
  int tx = threadIdx.x, ty = threadIdx.y;
#pragma unroll
  for (int j = 0; j < 4; ++j)
    t[ty + j * 8][tx] = W[(size_t)(k0 + ty + j * 8) * N + n0 + tx];
  __syncthreads();
#pragma unroll
  for (int j = 0; j < 4; ++j)
    Wt[(size_t)(n0 + ty + j * 8) * K + k0 + tx] = f2bf(t[tx][ty + j * 8]);
}

// ---------------------------------------------------------------- posenc + layernorm
template <bool PE>
__global__ __launch_bounds__(256) void ln_row(const float* __restrict__ in,
                                              const float* __restrict__ g,
                                              const float* __restrict__ be,
                                              float* __restrict__ xout,
                                              u16* __restrict__ hout) {
  const int row = blockIdx.x;
  const int tid = threadIdx.x;
  const int s = row & 2047;
  float4 xv = *(const float4*)&in[(size_t)row * 1024 + tid * 4];
  float vals[4];
  const float* xp = (const float*)&xv;
#pragma unroll
  for (int j = 0; j < 4; ++j) {
    float v = xp[j];
    if (PE) {
      int d = tid * 4 + j;
      float freq = powf(10000.f, -2.f * (float)d * (1.f / 1024.f));
      float ang = (float)s * freq;
      v += (d & 1) ? cosf(ang) : sinf(ang);
    }
    vals[j] = v;
  }
  if (PE) {
    float4 st;
    float* sp = (float*)&st;
#pragma unroll
    for (int j = 0; j < 4; ++j) sp[j] = vals[j];
    *(float4*)&xout[(size_t)row * 1024 + tid * 4] = st;
  }
  float sum = vals[0] + vals[1] + vals[2] + vals[3];
  float sq = vals[0] * vals[0] + vals[1] * vals[1] + vals[2] * vals[2] + vals[3] * vals[3];
#pragma unroll
  for (int d = 1; d < 64; d <<= 1) {
    sum += __shfl_xor(sum, d);
    sq += __shfl_xor(sq, d);
  }
  __shared__ float red[8];
  int wave = tid >> 6, lane = tid & 63;
  if (lane == 0) { red[wave] = sum; red[4 + wave] = sq; }
  __syncthreads();
  sum = red[0] + red[1] + red[2] + red[3];
  sq = red[4] + red[5] + red[6] + red[7];
  float mu = sum * (1.f / 1024.f);
  float var = sq * (1.f / 1024.f) - mu * mu;
  float rv = rsqrtf(var + 1e-5f);
#pragma unroll
  for (int j = 0; j < 4; ++j) {
    int d = tid * 4 + j;
    hout[(size_t)row * 1024 + d] = f2bf((vals[j] - mu) * rv * g[d] + be[d]);
  }
}

// ---------------------------------------------------------------- GEMM  C = A @ Bt^T
// 128x128 tile, BK=64, 4 waves, 4 blocks/CU, swizzled, 0 conflicts.
// Grids (24,64)/(8,64) -- measured best (R13/R15).
#define EPI_QKV 0
#define EPI_OPROJ 1
#define EPI_FFN1 2
#define EPI_FFN2 3

template <int EPI>
__global__ __launch_bounds__(256, 4) void gemm_bt(
    const u16* __restrict__ A, const u16* __restrict__ Bt, int M, int N, int K,
    const float* __restrict__ bias, const float* __restrict__ resid,
    float* __restrict__ outf, u16* __restrict__ outb,
    u16* __restrict__ oq, u16* __restrict__ okk, u16* __restrict__ ovt) {
  __shared__ __align__(16) u16 As[128 * 64];
  __shared__ __align__(16) u16 Bs[128 * 64];
  const int tid = threadIdx.x;
  const int wave = tid >> 6, lane = tid & 63;
  const int m0 = blockIdx.y * 128, n0 = blockIdx.x * 128;
  const int lrow = lane & 15, lhi = lane >> 4;
  const int wr = (wave >> 1) * 64, wc = (wave & 1) * 64;
  const int srow = tid >> 3;
  const int swsrc = ((tid & 7) ^ (srow & 7)) * 8;
  const u16* Ag = A + (size_t)(m0 + srow) * K + swsrc;
  const u16* Bg = Bt + (size_t)(n0 + srow) * K + swsrc;

  f32x4 acc[4][4] = {};

  for (int kt = 0; kt < K; kt += 64) {
#pragma unroll
    for (int j = 0; j < 4; ++j) {
      GLOAD16(Ag + (size_t)(j * 32) * K + kt, &As[j * 2048 + wave * 512]);
      GLOAD16(Bg + (size_t)(j * 32) * K + kt, &Bs[j * 2048 + wave * 512]);
    }
    __syncthreads();
    bf16x8 af[2][4], bfr[2][4];
#pragma unroll
    for (int kk = 0; kk < 2; ++kk) {
#pragma unroll
      for (int m = 0; m < 4; ++m)
        af[kk][m] = *(const bf16x8*)&As[SW(wr + m * 16 + lrow, kk * 4 + lhi)];
#pragma unroll
      for (int n = 0; n < 4; ++n)
        bfr[kk][n] = *(const bf16x8*)&Bs[SW(wc + n * 16 + lrow, kk * 4 + lhi)];
    }
#pragma unroll
    for (int kk = 0; kk < 2; ++kk)
#pragma unroll
      for (int m = 0; m < 4; ++m)
#pragma unroll
        for (int n = 0; n < 4; ++n)
          acc[m][n] = __builtin_amdgcn_mfma_f32_16x16x32_bf16(af[kk][m], bfr[kk][n], acc[m][n], 0, 0, 0);
    __syncthreads();
  }

#pragma unroll
  for (int m = 0; m < 4; ++m) {
#pragma unroll
    for (int n = 0; n < 4; ++n) {
#pragma unroll
      for (int i = 0; i < 4; ++i) {
        int row = m0 + wr + m * 16 + lhi * 4 + i;
        int col = n0 + wc + n * 16 + lrow;
        float v = acc[m][n][i];
        if (EPI == EPI_QKV) {
          int which = col >> 10, c = col & 1023;
          int h = c >> 6, hd = c & 63;
          int b = row >> 11, s = row & 2047;
          size_t qk = (((size_t)(b * 16 + h) * 2048 + s) << 6) + hd;
          if (which == 0) oq[qk] = f2bf(v * QSCALE);
          else if (which == 1) okk[qk] = f2bf(v);
          else ovt[((size_t)(b * 16 + h) * 64 + hd) * 2048 + s] = f2bf(v);
        } else if (EPI == EPI_OPROJ) {
          size_t idx = (size_t)row * 1024 + col;
          outf[idx] = v + resid[idx];
        } else if (EPI == EPI_FFN1) {
          float t = v + bias[col];
          t = t > 0.f ? t : 0.01f * t;
          outb[(size_t)row * 3072 + col] = f2bf(t);
        } else {  // FFN2
          size_t idx = (size_t)row * 1024 + col;
          outf[idx] = v + bias[col] + resid[idx];
        }
      }
    }
  }
}

// ---------------------------------------------------------------- flash attention
// KVBLK=128: 16 tiles of 128 kv (vs 32 of 64) -- halves barrier epochs,
// doubles MFMA+exp per epoch (the dose that helped GEMM BK 32->64).
// 4-wave / 128-q-row blocks, 1024 blocks.  LDS 80KB (K dbuf 2x16K, V single
// 16K, P 128x128 32K) -> 2 blocks/CU (R17/R18 showed 2 vs 4 blocks neutral).
// P uses a 128-wide swizzle (16 chunks, XOR r&15, same involution both
// sides).  NOTE: 128-wide P overlaps other waves' staged-Q regions -> one
// extra __syncthreads after qf extraction.  __expf softmax, no-max, XCD remap.
__global__ __launch_bounds__(256, 2) void attn_fwd(const u16* __restrict__ qb,
                                                   const u16* __restrict__ kbuf,
                                                   const u16* __restrict__ vtb,
                                                   u16* __restrict__ ob) {
  __shared__ __align__(16) u16 Kl[2][128 * 64];
  __shared__ __align__(16) u16 Vl[64 * 128];
  __shared__ __align__(16) u16 Pl[128 * 128];
  const int tid = threadIdx.x, wave = tid >> 6, lane = tid & 63;
  const int wid = (blockIdx.x & 7) * 128 + (blockIdx.x >> 3);
  const int bh = wid >> 4, qt = wid & 15;
  const int lrow = lane & 15, lhi = lane >> 4;
  const u16* Qg = qb + (((size_t)bh * 2048 + qt * 128) << 6);
  const u16* Kg = kbuf + ((size_t)bh * 2048 << 6);
  const u16* Vg = vtb + (size_t)bh * 64 * 2048;
  const int srow = tid >> 3;                       // K/Q staging row 0..31 (+j*32)
  const int swsrc = ((tid & 7) ^ (srow & 7)) * 8;  // pre-swizzled src chunk (8-chunk rows)
  const int vrow0 = wave * 4 + (lane >> 4);        // V staging row 0..15 (+j*16)
  const int vchunk = lane & 15;                    // V src chunk (16-chunk rows)

  // stage Q (64-wide layout into Pl[0..8191]), K tile0, V tile0
#pragma unroll
  for (int j = 0; j < 4; ++j)
    GLOAD16(Qg + (size_t)(srow + j * 32) * 64 + swsrc, &Pl[j * 2048 + wave * 512]);
#pragma unroll
  for (int j = 0; j < 4; ++j)
    GLOAD16(Kg + (size_t)(srow + j * 32) * 64 + swsrc, &Kl[0][j * 2048 + wave * 512]);
#pragma unroll
  for (int j = 0; j < 4; ++j) {
    int vr = vrow0 + j * 16;
    GLOAD16(Vg + (size_t)vr * 2048 + ((vchunk ^ (vr & 15)) * 8), &Vl[j * 2048 + wave * 512]);
  }
  __syncthreads();

  bf16x8 qf[2][2];
#pragma unroll
  for (int m = 0; m < 2; ++m)
#pragma unroll
    for (int kk = 0; kk < 2; ++kk)
      qf[m][kk] = *(const bf16x8*)&Pl[SW(wave * 32 + m * 16 + lrow, kk * 4 + lhi)];
  __syncthreads();  // all waves' qf extracted before P (128-wide) overwrites Q regions

  f32x4 oacc[2][4] = {};
  float lsum[8];
#pragma unroll
  for (int i = 0; i < 8; ++i) lsum[i] = 0.f;

  int cur = 0;
  for (int kv = 0; kv < 2048; kv += 128) {
    if (kv) __syncthreads();  // K[cur] + V (staged last tile) landed
    if (kv + 128 < 2048) {    // K prefetch flies under this whole tile
#pragma unroll
      for (int j = 0; j < 4; ++j)
        GLOAD16(Kg + (size_t)(kv + 128 + srow + j * 32) * 64 + swsrc,
                &Kl[cur ^ 1][j * 2048 + wave * 512]);
    }

    // QK^T: 8 n-frags over 128 kv rows
    f32x4 sf[2][8] = {};
#pragma unroll
    for (int n = 0; n < 8; ++n) {
#pragma unroll
      for (int kk = 0; kk < 2; ++kk) {
        bf16x8 kf = *(const bf16x8*)&Kl[cur][SW(n * 16 + lrow, kk * 4 + lhi)];
        sf[0][n] = __builtin_amdgcn_mfma_f32_16x16x32_bf16(qf[0][kk], kf, sf[0][n], 0, 0, 0);
        sf[1][n] = __builtin_amdgcn_mfma_f32_16x16x32_bf16(qf[1][kk], kf, sf[1][n], 0, 0, 0);
      }
    }
    // no-max softmax: p = exp(s); per-lane partial row-sums only
#pragma unroll
    for (int m = 0; m < 2; ++m) {
#pragma unroll
      for (int i = 0; i < 4; ++i) {
        float rs = 0.f;
#pragma unroll
        for (int n = 0; n < 8; ++n) {
          float p = __expf(sf[m][n][i]);
          sf[m][n][i] = p;
          rs += p;
        }
        lsum[m * 4 + i] += rs;
      }
    }
    // P -> LDS (bf16, 128-wide swizzle, wave-private rows)
#pragma unroll
    for (int m = 0; m < 2; ++m)
#pragma unroll
      for (int n = 0; n < 8; ++n)
#pragma unroll
        for (int i = 0; i < 4; ++i) {
          int pr = wave * 32 + m * 16 + lhi * 4 + i;
          Pl[(pr << 7) + ((((n * 2 + (lrow >> 3)) ^ (pr & 15))) << 3) + (lrow & 7)] =
              f2bf(sf[m][n][i]);
        }
    // PV over 4 kk chunks of 128 kv
#pragma unroll
    for (int kk = 0; kk < 4; ++kk) {
      bf16x8 pf0 = *(const bf16x8*)&Pl[SW128(wave * 32 + 0 + lrow, kk * 4 + lhi)];
      bf16x8 pf1 = *(const bf16x8*)&Pl[SW128(wave * 32 + 16 + lrow, kk * 4 + lhi)];
#pragma unroll
      for (int n = 0; n < 4; ++n) {
        bf16x8 vf = *(const bf16x8*)&Vl[SW128(n * 16 + lrow, kk * 4 + lhi)];
        oacc[0][n] = __builtin_amdgcn_mfma_f32_16x16x32_bf16(pf0, vf, oacc[0][n], 0, 0, 0);
        oacc[1][n] = __builtin_amdgcn_mfma_f32_16x16x32_bf16(pf1, vf, oacc[1][n], 0, 0, 0);
      }
    }
    __syncthreads();          // all waves done reading Vl -> safe to re-stage
    if (kv + 128 < 2048) {    // V stage; lands by next tile-start barrier
#pragma unroll
      for (int j = 0; j < 4; ++j) {
        int vr = vrow0 + j * 16;
        GLOAD16(Vg + (size_t)vr * 2048 + kv + 128 + ((vchunk ^ (vr & 15)) * 8),
                &Vl[j * 2048 + wave * 512]);
      }
    }
    cur ^= 1;
  }

#pragma unroll
  for (int idx = 0; idx < 8; ++idx)
#pragma unroll
    for (int d = 1; d < 16; d <<= 1)
      lsum[idx] += __shfl_xor(lsum[idx], d, 16);

  const int b = bh >> 4, h = bh & 15;
#pragma unroll
  for (int m = 0; m < 2; ++m)
#pragma unroll
    for (int i = 0; i < 4; ++i) {
      int qrow = qt * 128 + wave * 32 + m * 16 + lhi * 4 + i;
      float inv = 1.f / lsum[m * 4 + i];
#pragma unroll
      for (int n = 0; n < 4; ++n) {
        int hd = n * 16 + lrow;
        ob[((size_t)(b * 2048 + qrow)) * 1024 + h * 64 + hd] = f2bf(oacc[m][n][i] * inv);
      }
    }
}

// ---------------------------------------------------------------- launch
extern "C" void kernel_launch(void* const* d_in, const int* in_sizes, int n_in,
                              void* d_out, int out_size, void* d_ws, size_t ws_size,
                              hipStream_t stream) {
  const float* x = (const float*)d_in[0];
  const float* Wq = (const float*)d_in[1];
  const float* Wk = (const float*)d_in[2];
  const float* Wv = (const float*)d_in[3];
  const float* Wo = (const float*)d_in[4];
  const float* W1 = (const float*)d_in[5];
  const float* b1 = (const float*)d_in[6];
  const float* W2 = (const float*)d_in[7];
  const float* b2 = (const float*)d_in[8];
  const float* g1 = (const float*)d_in[9];
  const float* be1 = (const float*)d_in[10];
  const float* g2 = (const float*)d_in[11];
  const float* be2 = (const float*)d_in[12];

  char* ws = (char*)d_ws;
  const size_t MB = 1024 * 1024;
  float* x1 = (float*)(ws + 0);          // 32MB, becomes x2 in-place after OPROJ
  u16* h = (u16*)(ws + 32 * MB);         // 16MB (reused as h2)
  u16* q = (u16*)(ws + 48 * MB);         // 16MB
  u16* k = (u16*)(ws + 64 * MB);         // 16MB
  u16* vt = (u16*)(ws + 80 * MB);        // 16MB
  u16* o = (u16*)(ws + 96 * MB);         // 16MB
  u16* f = (u16*)(ws + 48 * MB);         // 48MB, aliases q/k/vt (dead after attn)
  u16* wqkv = (u16*)(ws + 112 * MB);     // 6MB
  u16* wo = (u16*)(ws + 118 * MB);       // 2MB
  u16* w1t = (u16*)(ws + 120 * MB);      // 6MB
  u16* w2t = (u16*)(ws + 126 * MB);      // 6MB -> 132MB total
  float* out = (float*)d_out;

  tconv_all<<<10240, dim3(32, 8), 0, stream>>>(Wq, Wk, Wv, Wo, W1, W2,
                                               wqkv, wo, w1t, w2t);

  ln_row<true><<<8192, 256, 0, stream>>>(x, g1, be1, x1, h);

  gemm_bt<EPI_QKV><<<dim3(24, 64), 256, 0, stream>>>(h, wqkv, 8192, 3072, 1024,
                                                     nullptr, nullptr, nullptr, nullptr,
                                                     q, k, vt);
  attn_fwd<<<1024, 256, 0, stream>>>(q, k, vt, o);

  gemm_bt<EPI_OPROJ><<<dim3(8, 64), 256, 0, stream>>>(o, wo, 8192, 1024, 1024,
                                                      nullptr, x1, x1, nullptr,
                                                      nullptr, nullptr, nullptr);
  ln_row<false><<<8192, 256, 0, stream>>>(x1, g2, be2, nullptr, h);

  gemm_bt<EPI_FFN1><<<dim3(24, 64), 256, 0, stream>>>(h, w1t, 8192, 3072, 1024,
                                                      b1, nullptr, nullptr, f,
                                                      nullptr, nullptr, nullptr);
  gemm_bt<EPI_FFN2><<<dim3(8, 64), 256, 0, stream>>>(f, w2t, 8192, 1024, 3072,
                                                     b2, x1, out, nullptr,
                                                     nullptr, nullptr, nullptr);
}